// Round 6
// baseline (294.075 us; speedup 1.0000x reference)
//
#include <hip/hip_runtime.h>
#include <hip/hip_bf16.h>

#define MD 8192
#define KD 4096
#define ND 4096

typedef __bf16 bf16x8 __attribute__((ext_vector_type(8)));
typedef float f32x4 __attribute__((ext_vector_type(4)));

__device__ __forceinline__ float gelu_ss(float v) {
    float t = 0.7978845608f * fmaf(0.044715f * v * v, v, v);
    float r = t * __builtin_amdgcn_rcpf(1.0f + fabsf(t));
    return 0.5f * v * (1.0f + r);
}

// ---------------------------------------------------------------------------
// fp32 -> bf16 convert (memory-bound; inputs are L3-resident after 1st replay)
// ---------------------------------------------------------------------------
__global__ void cvt_bf16(const float* __restrict__ in, __bf16* __restrict__ out, int n8) {
    int i = blockIdx.x * 256 + threadIdx.x;
    int stride = gridDim.x * 256;
    for (; i < n8; i += stride) {
        const float4* p = (const float4*)(in + (size_t)i * 8);
        float4 a = p[0], b = p[1];
        bf16x8 v;
        v[0]=(__bf16)a.x; v[1]=(__bf16)a.y; v[2]=(__bf16)a.z; v[3]=(__bf16)a.w;
        v[4]=(__bf16)b.x; v[5]=(__bf16)b.y; v[6]=(__bf16)b.z; v[7]=(__bf16)b.w;
        *(bf16x8*)(out + (size_t)i * 8) = v;
    }
}

// ---------------------------------------------------------------------------
// GEMM+epilogue: 256x256, BK=64, 2 LDS bufs, m201-faithful cadence:
// per K-tile 4 phases x [reads||stage, BAR1, lgkm0, 16 MFMA, BAR2],
// balanced reads 8/8/4/4, vmcnt(4)+BARtop replacing p3's BAR2 (8 bar/tile).
// ---------------------------------------------------------------------------
#define BMg 256
#define BNg 256
#define BKg 64
#define KTg (KD / BKg)   // 64

__device__ __forceinline__ void gload_lds16(const void* g, void* l) {
    __builtin_amdgcn_global_load_lds(
        (const __attribute__((address_space(1))) void*)g,
        (__attribute__((address_space(3))) void*)l, 16, 0, 0);
}

__global__ __launch_bounds__(512, 1) void gemm_bf16_lse(
    const __bf16* __restrict__ xb, const __bf16* __restrict__ Wb,
    const float* __restrict__ bias, float* __restrict__ rowsum)
{
    // [buf][A=0/B=1][256*64 bf16] = 128 KiB
    __shared__ alignas(16) __bf16 lds[2][2][BMg * BKg];

    const unsigned nblk = (MD / BMg) * (ND / BNg);   // 512
    unsigned bid  = blockIdx.x;
    unsigned sbid = (bid & 7u) * (nblk / 8u) + (bid >> 3);
    unsigned bm = sbid / (ND / BNg);
    unsigned bn = sbid % (ND / BNg);

    const unsigned tid  = threadIdx.x;
    const unsigned lane = tid & 63u;
    const unsigned wid  = tid >> 6;      // 0..7
    const unsigned wr   = wid >> 2;      // 0..1 -> 128 rows
    const unsigned wc   = wid & 3u;      // 0..3 -> 64 cols
    const unsigned lr   = lane & 15u;
    const unsigned kg   = lane >> 4;
    const unsigned x7   = lr & 7u;       // row-derived swizzle bits

    // staging: chunk ch -> row = ch>>3, slot = ch&7; LDS linear (DMA),
    // global col-slot pre-swizzled cg = slot ^ (row&7)  (rule #21).
    unsigned ch0 = tid, ch1 = tid + 512u;
    unsigned sr0 = ch0 >> 3, cg0 = (ch0 & 7u) ^ (sr0 & 7u);
    unsigned sr1 = ch1 >> 3, cg1 = (ch1 & 7u) ^ (sr1 & 7u);
    const __bf16* gA0 = xb + (size_t)(bm * BMg + sr0) * KD + cg0 * 8u;
    const __bf16* gA1 = xb + (size_t)(bm * BMg + sr1) * KD + cg1 * 8u;
    const __bf16* gB0 = Wb + (size_t)(bn * BNg + sr0) * KD + cg0 * 8u;
    const __bf16* gB1 = Wb + (size_t)(bn * BNg + sr1) * KD + cg1 * 8u;

    f32x4 acc[8][4] = {};

    auto stA = [&](unsigned bsel, unsigned half, int t) {
        size_t off = (size_t)half * 128u * KD + (size_t)t * 64u;
        gload_lds16(gA0 + off, &lds[bsel][0][(half * 1024u + ch0) * 8u]);
        gload_lds16(gA1 + off, &lds[bsel][0][(half * 1024u + ch1) * 8u]);
    };
    auto stB = [&](unsigned bsel, unsigned half, int t) {
        size_t off = (size_t)half * 128u * KD + (size_t)t * 64u;
        gload_lds16(gB0 + off, &lds[bsel][1][(half * 1024u + ch0) * 8u]);
        gload_lds16(gB1 + off, &lds[bsel][1][(half * 1024u + ch1) * 8u]);
    };
    // fragment reads; row stride 128B, slot (ks*4+kg) swizzled by row&7
    auto loadBks = [&](unsigned bsel, unsigned ks, bf16x8* dst) {
        const char* Bs = (const char*)&lds[bsel][1][0];
        #pragma unroll
        for (int nf = 0; nf < 4; ++nf) {
            unsigned ro = (wc * 64u + nf * 16u + lr) * 128u;
            dst[nf] = *(const bf16x8*)(Bs + ro + ((ks * 4u + kg) ^ x7) * 16u);
        }
    };
    auto loadAq = [&](unsigned bsel, unsigned mh, unsigned ks, bf16x8* dst) {
        const char* As = (const char*)&lds[bsel][0][0];
        #pragma unroll
        for (int a = 0; a < 4; ++a) {
            unsigned ro = (wr * 128u + (mh * 4u + a) * 16u + lr) * 128u;
            dst[a] = *(const bf16x8*)(As + ro + ((ks * 4u + kg) ^ x7) * 16u);
        }
    };
    auto mfmaQ = [&](unsigned mh, const bf16x8* a4, const bf16x8* b4) {
        __builtin_amdgcn_s_setprio(1);
        #pragma unroll
        for (int a = 0; a < 4; ++a)
            #pragma unroll
            for (int nf = 0; nf < 4; ++nf)
                acc[mh * 4 + a][nf] = __builtin_amdgcn_mfma_f32_16x16x32_bf16(
                    a4[a], b4[nf], acc[mh * 4 + a][nf], 0, 0, 0);
        __builtin_amdgcn_s_setprio(0);
    };

    // prologue: B(0), A(0) -> buf0; B(1) -> buf1.  12 gloads/thread in flight.
    stB(0, 0, 0); stB(0, 1, 0);
    stA(0, 0, 0); stA(0, 1, 0);
    stB(1, 0, 1); stB(1, 1, 1);

    for (int t = 0; t < KTg; ++t) {
        unsigned cb = (unsigned)t & 1u;
        bf16x8 a0[4], a1[4], b0v[4], b1v[4];
        // ---- BARtop: tile t staged chip-wide (counted vmcnt, never 0 mid-loop)
        if (t < KTg - 1) asm volatile("s_waitcnt vmcnt(4)" ::: "memory");
        else             asm volatile("s_waitcnt vmcnt(0)" ::: "memory");
        __builtin_amdgcn_s_barrier();

        // ---- p0: B[ks0](4) + A[m0-3,ks0](4); stage A(t+1) half0 ----
        loadBks(cb, 0, b0v);
        loadAq(cb, 0, 0, a0);
        if (t + 1 < KTg) stA(cb ^ 1u, 0, t + 1);
        __builtin_amdgcn_sched_barrier(0);
        __builtin_amdgcn_s_barrier();
        asm volatile("s_waitcnt lgkmcnt(0)" ::: "memory");
        mfmaQ(0, a0, b0v);
        __builtin_amdgcn_s_barrier();
        // ---- p1: A[m4-7,ks0](4) + B[ks1](4); stage A(t+1) half1 ----
        loadAq(cb, 1, 0, a1);
        loadBks(cb, 1, b1v);
        if (t + 1 < KTg) stA(cb ^ 1u, 1, t + 1);
        __builtin_amdgcn_sched_barrier(0);
        __builtin_amdgcn_s_barrier();
        asm volatile("s_waitcnt lgkmcnt(0)" ::: "memory");
        mfmaQ(1, a1, b0v);
        __builtin_amdgcn_s_barrier();
        // ---- p2: A[m0-3,ks1](4); stage B(t+2) half0 (B reads drained @p1 BAR2)
        loadAq(cb, 0, 1, a0);
        if (t + 2 < KTg) stB(cb, 0, t + 2);
        __builtin_amdgcn_sched_barrier(0);
        __builtin_amdgcn_s_barrier();
        asm volatile("s_waitcnt lgkmcnt(0)" ::: "memory");
        mfmaQ(0, a0, b1v);
        __builtin_amdgcn_s_barrier();
        // ---- p3: A[m4-7,ks1](4); stage B(t+2) half1 ----
        loadAq(cb, 1, 1, a1);
        if (t + 2 < KTg) stB(cb, 1, t + 2);
        __builtin_amdgcn_sched_barrier(0);
        __builtin_amdgcn_s_barrier();
        asm volatile("s_waitcnt lgkmcnt(0)" ::: "memory");
        mfmaQ(1, a1, b1v);
        // no BAR2: next iteration's vmcnt+BARtop re-syncs (reads drained above)
    }

    // ---- epilogue: bias + leaky^2 + gelu^2 + exp + row partial sums ----
    // C/D layout: col = lane&15 (=lr), row = kg*4 + j
    unsigned row_base = bm * BMg + wr * 128u;
    unsigned col_base = bn * BNg + wc * 64u;
    float bb[4];
    #pragma unroll
    for (int nf = 0; nf < 4; ++nf) bb[nf] = bias[col_base + nf * 16u + lr];
    #pragma unroll
    for (int mf = 0; mf < 8; ++mf) {
        float s[4] = {0.f, 0.f, 0.f, 0.f};
        #pragma unroll
        for (int nf = 0; nf < 4; ++nf) {
            #pragma unroll
            for (int j = 0; j < 4; ++j) {
                float v = acc[mf][nf][j] + bb[nf];
                v = v > 0.0f ? v : 1e-4f * v;      // two leaky-relus fused
                v = gelu_ss(gelu_ss(v));
                s[j] += __expf(v);
            }
        }
        #pragma unroll
        for (int j = 0; j < 4; ++j) {
            float t = s[j];
            t += __shfl_xor(t, 1);
            t += __shfl_xor(t, 2);
            t += __shfl_xor(t, 4);
            t += __shfl_xor(t, 8);
            if (lr == 0)
                atomicAdd(&rowsum[row_base + mf * 16u + kg * 4u + j], t);
        }
    }
}

// ---------------------------------------------------------------------------
// Fallback (round-2 kernel): fused fp32 staging, used only if ws too small.
// ---------------------------------------------------------------------------
#define BM 256
#define BN 256
#define BK 64
#define NBLK ((MD / BM) * (ND / BN))

__device__ __forceinline__ unsigned swz(unsigned row, unsigned kbyte) {
    return row * (BK * 2u) + (kbyte ^ ((row & 7u) << 4));
}

__global__ __launch_bounds__(512, 1) void fused_gemm_lse(
    const float* __restrict__ x, const float* __restrict__ W,
    const float* __restrict__ bias, float* __restrict__ rowsum)
{
    __shared__ alignas(16) __bf16 lds[2][2][BM * BK];
    unsigned bid  = blockIdx.x;
    unsigned sbid = (bid & 7u) * (NBLK / 8u) + (bid >> 3);
    unsigned bm = sbid / (ND / BN);
    unsigned bn = sbid % (ND / BN);
    const unsigned tid  = threadIdx.x;
    const unsigned lane = tid & 63u;
    const unsigned wid  = tid >> 6;
    const unsigned wr   = wid >> 2;
    const unsigned wc   = wid & 3u;
    const unsigned lr   = lane & 15u;
    const unsigned kg   = lane >> 4;
    const float* gA = x + (size_t)bm * BM * KD;
    const float* gB = W + (size_t)bn * BN * KD;
    const unsigned s_row = tid >> 3;
    const unsigned s_c8  = tid & 7u;
    f32x4 acc[8][4] = {};
    float4 ra[8], rb[8];
    auto issue = [&](const float* g, int kt, float4* r) {
        #pragma unroll
        for (int i = 0; i < 4; ++i) {
            unsigned row = s_row + 64u * i;
            size_t goff = (size_t)row * KD + (size_t)kt * BK + (size_t)s_c8 * 8u;
            r[i * 2]     = *(const float4*)(g + goff);
            r[i * 2 + 1] = *(const float4*)(g + goff + 4);
        }
    };
    auto writeT = [&](char* dst, const float4* r) {
        #pragma unroll
        for (int i = 0; i < 4; ++i) {
            unsigned row = s_row + 64u * i;
            float4 lo = r[i * 2], hi = r[i * 2 + 1];
            bf16x8 v;
            v[0]=(__bf16)lo.x; v[1]=(__bf16)lo.y; v[2]=(__bf16)lo.z; v[3]=(__bf16)lo.w;
            v[4]=(__bf16)hi.x; v[5]=(__bf16)hi.y; v[6]=(__bf16)hi.z; v[7]=(__bf16)hi.w;
            *(bf16x8*)(dst + swz(row, s_c8 * 16u)) = v;
        }
    };
    auto compute = [&](int cur) {
        const char* AsB = (const char*)&lds[cur][0][0];
        const char* BsB = (const char*)&lds[cur][1][0];
        #pragma unroll
        for (int ks = 0; ks < 2; ++ks) {
            unsigned kb = (unsigned)ks * 64u + kg * 16u;
            bf16x8 bfr[4];
            #pragma unroll
            for (int ni = 0; ni < 4; ++ni)
                bfr[ni] = *(const bf16x8*)(BsB + swz(wc * 64u + ni * 16u + lr, kb));
            #pragma unroll
            for (int mh = 0; mh < 2; ++mh) {
                bf16x8 af[4];
                #pragma unroll
                for (int a = 0; a < 4; ++a)
                    af[a] = *(const bf16x8*)(AsB + swz(wr * 128u + mh * 64u + a * 16u + lr, kb));
                __builtin_amdgcn_s_setprio(1);
                #pragma unroll
                for (int a = 0; a < 4; ++a)
                    #pragma unroll
                    for (int ni = 0; ni < 4; ++ni)
                        acc[mh * 4 + a][ni] = __builtin_amdgcn_mfma_f32_16x16x32_bf16(
                            af[a], bfr[ni], acc[mh * 4 + a][ni], 0, 0, 0);
                __builtin_amdgcn_s_setprio(0);
            }
        }
    };
    issue(gA, 0, ra); issue(gB, 0, rb);
    writeT((char*)&lds[0][0][0], ra);
    writeT((char*)&lds[0][1][0], rb);
    __syncthreads();
    int cur = 0;
    for (int kt = 0; kt < KD / BK - 1; ++kt) {
        issue(gA, kt + 1, ra);
        issue(gB, kt + 1, rb);
        compute(cur);
        writeT((char*)&lds[cur ^ 1][0][0], ra);
        writeT((char*)&lds[cur ^ 1][1][0], rb);
        __syncthreads();
        cur ^= 1;
    }
    compute(cur);
    unsigned row_base = bm * BM + wr * 128u;
    unsigned col_base = bn * BN + wc * 64u;
    float bb[4];
    #pragma unroll
    for (int ni = 0; ni < 4; ++ni) bb[ni] = bias[col_base + ni * 16u + lr];
    #pragma unroll
    for (int mi = 0; mi < 8; ++mi) {
        float s[4] = {0.f, 0.f, 0.f, 0.f};
        #pragma unroll
        for (int ni = 0; ni < 4; ++ni) {
            #pragma unroll
            for (int j = 0; j < 4; ++j) {
                float v = acc[mi][ni][j] + bb[ni];
                v = v > 0.0f ? v : 1e-4f * v;
                v = gelu_ss(gelu_ss(v));
                s[j] += __expf(v);
            }
        }
        #pragma unroll
        for (int j = 0; j < 4; ++j) {
            float t = s[j];
            t += __shfl_xor(t, 1);
            t += __shfl_xor(t, 2);
            t += __shfl_xor(t, 4);
            t += __shfl_xor(t, 8);
            if (lr == 0)
                atomicAdd(&rowsum[row_base + mi * 16u + kg * 4u + j], t);
        }
    }
}

__global__ void lse_log(float* __restrict__ out) {
    int i = blockIdx.x * 256 + threadIdx.x;
    if (i < MD) out[i] = logf(out[i]);
}

extern "C" void kernel_launch(void* const* d_in, const int* in_sizes, int n_in,
                              void* d_out, int out_size, void* d_ws, size_t ws_size,
                              hipStream_t stream) {
    (void)in_sizes; (void)n_in; (void)out_size;
    const float* x = (const float*)d_in[0];
    const float* W = (const float*)d_in[1];
    const float* b = (const float*)d_in[2];
    float* out = (float*)d_out;

    hipMemsetAsync(out, 0, (size_t)MD * sizeof(float), stream);

    size_t need = ((size_t)MD * KD + (size_t)ND * KD) * sizeof(__bf16);  // 100.7 MB
    if (ws_size >= need) {
        __bf16* xb = (__bf16*)d_ws;
        __bf16* Wb = xb + (size_t)MD * KD;
        cvt_bf16<<<2048, 256, 0, stream>>>(x, xb, MD * KD / 8);
        cvt_bf16<<<2048, 256, 0, stream>>>(W, Wb, ND * KD / 8);
        gemm_bf16_lse<<<(MD / BMg) * (ND / BNg), 512, 0, stream>>>(xb, Wb, b, out);
    } else {
        fused_gemm_lse<<<NBLK, 512, 0, stream>>>(x, W, b, out);
    }
    lse_log<<<MD / 256, 256, 0, stream>>>(out);
}

// Round 7
// 290.540 us; speedup vs baseline: 1.0122x; 1.0122x over previous
//
#include <hip/hip_runtime.h>
#include <hip/hip_bf16.h>

#define MD 8192
#define KD 4096
#define ND 4096

typedef __bf16 bf16x8 __attribute__((ext_vector_type(8)));
typedef float f32x4 __attribute__((ext_vector_type(4)));

__device__ __forceinline__ float gelu_ss(float v) {
    float t = 0.7978845608f * fmaf(0.044715f * v * v, v, v);
    float r = t * __builtin_amdgcn_rcpf(1.0f + fabsf(t));
    return 0.5f * v * (1.0f + r);
}

// ---------------------------------------------------------------------------
// fp32 -> bf16 convert (memory-bound; inputs are L3-resident after 1st replay)
// ---------------------------------------------------------------------------
__global__ void cvt_bf16(const float* __restrict__ in, __bf16* __restrict__ out, int n8) {
    int i = blockIdx.x * 256 + threadIdx.x;
    int stride = gridDim.x * 256;
    for (; i < n8; i += stride) {
        const float4* p = (const float4*)(in + (size_t)i * 8);
        float4 a = p[0], b = p[1];
        bf16x8 v;
        v[0]=(__bf16)a.x; v[1]=(__bf16)a.y; v[2]=(__bf16)a.z; v[3]=(__bf16)a.w;
        v[4]=(__bf16)b.x; v[5]=(__bf16)b.y; v[6]=(__bf16)b.z; v[7]=(__bf16)b.w;
        *(bf16x8*)(out + (size_t)i * 8) = v;
    }
}

// ---------------------------------------------------------------------------
// GEMM+epilogue: 256x256, BK=64, 2 LDS bufs.
// KEY CHANGE (r7): fragment-register double-buffering + counted lgkmcnt:
// slot p issues ds_reads for phase p+1, waits lgkmcnt(R_p) -> LDS drain of
// phase p+1's reads overlaps MFMA(p). One barrier per phase (post-MFMA).
// vmcnt(2) once per tile (after MFMA p2) certifies buf^1 for p3's read-ahead.
// ---------------------------------------------------------------------------
#define BMg 256
#define BNg 256
#define BKg 64
#define KTg (KD / BKg)   // 64

__device__ __forceinline__ void gload_lds16(const void* g, void* l) {
    __builtin_amdgcn_global_load_lds(
        (const __attribute__((address_space(1))) void*)g,
        (__attribute__((address_space(3))) void*)l, 16, 0, 0);
}

__global__ __launch_bounds__(512, 1) void gemm_bf16_lse(
    const __bf16* __restrict__ xb, const __bf16* __restrict__ Wb,
    const float* __restrict__ bias, float* __restrict__ rowsum)
{
    // [buf][A=0/B=1][256*64 bf16] = 128 KiB
    __shared__ alignas(16) __bf16 lds[2][2][BMg * BKg];

    const unsigned nblk = (MD / BMg) * (ND / BNg);   // 512
    unsigned bid  = blockIdx.x;
    unsigned sbid = (bid & 7u) * (nblk / 8u) + (bid >> 3);
    unsigned bm = sbid / (ND / BNg);
    unsigned bn = sbid % (ND / BNg);

    const unsigned tid  = threadIdx.x;
    const unsigned lane = tid & 63u;
    const unsigned wid  = tid >> 6;      // 0..7
    const unsigned wr   = wid >> 2;      // 0..1 -> 128 rows
    const unsigned wc   = wid & 3u;      // 0..3 -> 64 cols
    const unsigned lr   = lane & 15u;
    const unsigned kg   = lane >> 4;
    const unsigned x7   = lr & 7u;       // row-derived swizzle bits

    // staging: chunk ch -> row = ch>>3, slot = ch&7; LDS linear (DMA),
    // global col-slot pre-swizzled cg = slot ^ (row&7)  (rule #21).
    unsigned ch0 = tid, ch1 = tid + 512u;
    unsigned sr0 = ch0 >> 3, cg0 = (ch0 & 7u) ^ (sr0 & 7u);
    unsigned sr1 = ch1 >> 3, cg1 = (ch1 & 7u) ^ (sr1 & 7u);
    const __bf16* gA0 = xb + (size_t)(bm * BMg + sr0) * KD + cg0 * 8u;
    const __bf16* gA1 = xb + (size_t)(bm * BMg + sr1) * KD + cg1 * 8u;
    const __bf16* gB0 = Wb + (size_t)(bn * BNg + sr0) * KD + cg0 * 8u;
    const __bf16* gB1 = Wb + (size_t)(bn * BNg + sr1) * KD + cg1 * 8u;

    f32x4 acc[8][4] = {};

    auto stA = [&](unsigned bsel, unsigned half, int t) {
        size_t off = (size_t)half * 128u * KD + (size_t)t * 64u;
        gload_lds16(gA0 + off, &lds[bsel][0][(half * 1024u + ch0) * 8u]);
        gload_lds16(gA1 + off, &lds[bsel][0][(half * 1024u + ch1) * 8u]);
    };
    auto stB = [&](unsigned bsel, unsigned half, int t) {
        size_t off = (size_t)half * 128u * KD + (size_t)t * 64u;
        gload_lds16(gB0 + off, &lds[bsel][1][(half * 1024u + ch0) * 8u]);
        gload_lds16(gB1 + off, &lds[bsel][1][(half * 1024u + ch1) * 8u]);
    };
    // fragment reads; row stride 128B, slot (ks*4+kg) swizzled by row&7
    auto loadBks = [&](unsigned bsel, unsigned ks, bf16x8* dst) {
        const char* Bs = (const char*)&lds[bsel][1][0];
        #pragma unroll
        for (int nf = 0; nf < 4; ++nf) {
            unsigned ro = (wc * 64u + nf * 16u + lr) * 128u;
            dst[nf] = *(const bf16x8*)(Bs + ro + ((ks * 4u + kg) ^ x7) * 16u);
        }
    };
    auto loadAq = [&](unsigned bsel, unsigned mh, unsigned ks, bf16x8* dst) {
        const char* As = (const char*)&lds[bsel][0][0];
        #pragma unroll
        for (int a = 0; a < 4; ++a) {
            unsigned ro = (wr * 128u + (mh * 4u + a) * 16u + lr) * 128u;
            dst[a] = *(const bf16x8*)(As + ro + ((ks * 4u + kg) ^ x7) * 16u);
        }
    };
    auto mfmaQ = [&](unsigned mh, const bf16x8* a4, const bf16x8* b4) {
        __builtin_amdgcn_s_setprio(1);
        #pragma unroll
        for (int a = 0; a < 4; ++a)
            #pragma unroll
            for (int nf = 0; nf < 4; ++nf)
                acc[mh * 4 + a][nf] = __builtin_amdgcn_mfma_f32_16x16x32_bf16(
                    a4[a], b4[nf], acc[mh * 4 + a][nf], 0, 0, 0);
        __builtin_amdgcn_s_setprio(0);
    };

    bf16x8 aX[4], aY[4], bX[4], bY[4];

    // prologue: B(0), A(0) -> buf0; B(1) -> buf1.  12 gloads/thread in flight.
    stB(0, 0, 0); stB(0, 1, 0);
    stA(0, 0, 0); stA(0, 1, 0);
    stB(1, 0, 1); stB(1, 1, 1);
    asm volatile("s_waitcnt vmcnt(4)" ::: "memory");  // A(0),B(0) landed
    __builtin_amdgcn_s_barrier();
    // initial read-ahead for (0,p0): 8 reads outstanding
    loadBks(0, 0, bX);
    loadAq(0, 0, 0, aX);

    for (int t = 0; t < KTg; ++t) {
        unsigned cb = (unsigned)t & 1u;
        // ---- p0: reads->aY (m4-7,ks0); stage A(t+1)h0; MFMA(aX,bX) m0-3,ks0
        loadAq(cb, 1, 0, aY);
        if (t + 1 < KTg) stA(cb ^ 1u, 0, t + 1);
        __builtin_amdgcn_sched_barrier(0);
        asm volatile("s_waitcnt lgkmcnt(4)" ::: "memory");  // prev-slot reads done
        __builtin_amdgcn_sched_barrier(0);
        mfmaQ(0, aX, bX);
        __builtin_amdgcn_s_barrier();
        // ---- p1: reads->aX (m0-3,ks1) + bY (ks1); stage A(t+1)h1; MFMA(aY,bX)
        loadAq(cb, 0, 1, aX);
        loadBks(cb, 1, bY);
        if (t + 1 < KTg) stA(cb ^ 1u, 1, t + 1);
        __builtin_amdgcn_sched_barrier(0);
        asm volatile("s_waitcnt lgkmcnt(8)" ::: "memory");
        __builtin_amdgcn_sched_barrier(0);
        mfmaQ(1, aY, bX);
        // drain p1's reads (B(t)ks1) so stage-B@p2 can't race them chip-wide
        asm volatile("s_waitcnt lgkmcnt(0)" ::: "memory");
        __builtin_amdgcn_s_barrier();
        // ---- p2: reads->aY (m4-7,ks1); stage B(t+2)h0; MFMA(aX,bY) m0-3,ks1
        loadAq(cb, 1, 1, aY);
        if (t + 2 < KTg) stB(cb, 0, t + 2);
        __builtin_amdgcn_sched_barrier(0);
        asm volatile("s_waitcnt lgkmcnt(4)" ::: "memory");
        __builtin_amdgcn_sched_barrier(0);
        mfmaQ(0, aX, bY);
        // certify buf^1 (A(t+1) full + B(t+1) full) for p3's read-ahead
        if (t + 2 < KTg)      asm volatile("s_waitcnt vmcnt(2)" ::: "memory");
        else if (t + 1 < KTg) asm volatile("s_waitcnt vmcnt(0)" ::: "memory");
        __builtin_amdgcn_s_barrier();
        // ---- p3: reads->aX,bX from buf^1 (t+1 operands); stage B(t+2)h1;
        //          MFMA(aY,bY) m4-7,ks1
        if (t + 1 < KTg) {
            loadAq(cb ^ 1u, 0, 0, aX);
            loadBks(cb ^ 1u, 0, bX);
        }
        if (t + 2 < KTg) stB(cb, 1, t + 2);
        __builtin_amdgcn_sched_barrier(0);
        if (t + 1 < KTg) asm volatile("s_waitcnt lgkmcnt(8)" ::: "memory");
        else             asm volatile("s_waitcnt lgkmcnt(0)" ::: "memory");
        __builtin_amdgcn_sched_barrier(0);
        mfmaQ(1, aY, bY);
        __builtin_amdgcn_s_barrier();
    }

    // ---- epilogue: bias + leaky^2 + gelu^2 + exp + row partial sums ----
    // C/D layout: col = lane&15 (=lr), row = kg*4 + j
    unsigned row_base = bm * BMg + wr * 128u;
    unsigned col_base = bn * BNg + wc * 64u;
    float bb[4];
    #pragma unroll
    for (int nf = 0; nf < 4; ++nf) bb[nf] = bias[col_base + nf * 16u + lr];
    #pragma unroll
    for (int mf = 0; mf < 8; ++mf) {
        float s[4] = {0.f, 0.f, 0.f, 0.f};
        #pragma unroll
        for (int nf = 0; nf < 4; ++nf) {
            #pragma unroll
            for (int j = 0; j < 4; ++j) {
                float v = acc[mf][nf][j] + bb[nf];
                v = v > 0.0f ? v : 1e-4f * v;      // two leaky-relus fused
                v = gelu_ss(gelu_ss(v));
                s[j] += __expf(v);
            }
        }
        #pragma unroll
        for (int j = 0; j < 4; ++j) {
            float t = s[j];
            t += __shfl_xor(t, 1);
            t += __shfl_xor(t, 2);
            t += __shfl_xor(t, 4);
            t += __shfl_xor(t, 8);
            if (lr == 0)
                atomicAdd(&rowsum[row_base + mf * 16u + kg * 4u + j], t);
        }
    }
}

// ---------------------------------------------------------------------------
// Fallback (round-2 kernel): fused fp32 staging, used only if ws too small.
// ---------------------------------------------------------------------------
#define BM 256
#define BN 256
#define BK 64
#define NBLK ((MD / BM) * (ND / BN))

__device__ __forceinline__ unsigned swz(unsigned row, unsigned kbyte) {
    return row * (BK * 2u) + (kbyte ^ ((row & 7u) << 4));
}

__global__ __launch_bounds__(512, 1) void fused_gemm_lse(
    const float* __restrict__ x, const float* __restrict__ W,
    const float* __restrict__ bias, float* __restrict__ rowsum)
{
    __shared__ alignas(16) __bf16 lds[2][2][BM * BK];
    unsigned bid  = blockIdx.x;
    unsigned sbid = (bid & 7u) * (NBLK / 8u) + (bid >> 3);
    unsigned bm = sbid / (ND / BN);
    unsigned bn = sbid % (ND / BN);
    const unsigned tid  = threadIdx.x;
    const unsigned lane = tid & 63u;
    const unsigned wid  = tid >> 6;
    const unsigned wr   = wid >> 2;
    const unsigned wc   = wid & 3u;
    const unsigned lr   = lane & 15u;
    const unsigned kg   = lane >> 4;
    const float* gA = x + (size_t)bm * BM * KD;
    const float* gB = W + (size_t)bn * BN * KD;
    const unsigned s_row = tid >> 3;
    const unsigned s_c8  = tid & 7u;
    f32x4 acc[8][4] = {};
    float4 ra[8], rb[8];
    auto issue = [&](const float* g, int kt, float4* r) {
        #pragma unroll
        for (int i = 0; i < 4; ++i) {
            unsigned row = s_row + 64u * i;
            size_t goff = (size_t)row * KD + (size_t)kt * BK + (size_t)s_c8 * 8u;
            r[i * 2]     = *(const float4*)(g + goff);
            r[i * 2 + 1] = *(const float4*)(g + goff + 4);
        }
    };
    auto writeT = [&](char* dst, const float4* r) {
        #pragma unroll
        for (int i = 0; i < 4; ++i) {
            unsigned row = s_row + 64u * i;
            float4 lo = r[i * 2], hi = r[i * 2 + 1];
            bf16x8 v;
            v[0]=(__bf16)lo.x; v[1]=(__bf16)lo.y; v[2]=(__bf16)lo.z; v[3]=(__bf16)lo.w;
            v[4]=(__bf16)hi.x; v[5]=(__bf16)hi.y; v[6]=(__bf16)hi.z; v[7]=(__bf16)hi.w;
            *(bf16x8*)(dst + swz(row, s_c8 * 16u)) = v;
        }
    };
    auto compute = [&](int cur) {
        const char* AsB = (const char*)&lds[cur][0][0];
        const char* BsB = (const char*)&lds[cur][1][0];
        #pragma unroll
        for (int ks = 0; ks < 2; ++ks) {
            unsigned kb = (unsigned)ks * 64u + kg * 16u;
            bf16x8 bfr[4];
            #pragma unroll
            for (int ni = 0; ni < 4; ++ni)
                bfr[ni] = *(const bf16x8*)(BsB + swz(wc * 64u + ni * 16u + lr, kb));
            #pragma unroll
            for (int mh = 0; mh < 2; ++mh) {
                bf16x8 af[4];
                #pragma unroll
                for (int a = 0; a < 4; ++a)
                    af[a] = *(const bf16x8*)(AsB + swz(wr * 128u + mh * 64u + a * 16u + lr, kb));
                __builtin_amdgcn_s_setprio(1);
                #pragma unroll
                for (int a = 0; a < 4; ++a)
                    #pragma unroll
                    for (int ni = 0; ni < 4; ++ni)
                        acc[mh * 4 + a][ni] = __builtin_amdgcn_mfma_f32_16x16x32_bf16(
                            af[a], bfr[ni], acc[mh * 4 + a][ni], 0, 0, 0);
                __builtin_amdgcn_s_setprio(0);
            }
        }
    };
    issue(gA, 0, ra); issue(gB, 0, rb);
    writeT((char*)&lds[0][0][0], ra);
    writeT((char*)&lds[0][1][0], rb);
    __syncthreads();
    int cur = 0;
    for (int kt = 0; kt < KD / BK - 1; ++kt) {
        issue(gA, kt + 1, ra);
        issue(gB, kt + 1, rb);
        compute(cur);
        writeT((char*)&lds[cur ^ 1][0][0], ra);
        writeT((char*)&lds[cur ^ 1][1][0], rb);
        __syncthreads();
        cur ^= 1;
    }
    compute(cur);
    unsigned row_base = bm * BM + wr * 128u;
    unsigned col_base = bn * BN + wc * 64u;
    float bb[4];
    #pragma unroll
    for (int ni = 0; ni < 4; ++ni) bb[ni] = bias[col_base + ni * 16u + lr];
    #pragma unroll
    for (int mi = 0; mi < 8; ++mi) {
        float s[4] = {0.f, 0.f, 0.f, 0.f};
        #pragma unroll
        for (int ni = 0; ni < 4; ++ni) {
            #pragma unroll
            for (int j = 0; j < 4; ++j) {
                float v = acc[mi][ni][j] + bb[ni];
                v = v > 0.0f ? v : 1e-4f * v;
                v = gelu_ss(gelu_ss(v));
                s[j] += __expf(v);
            }
        }
        #pragma unroll
        for (int j = 0; j < 4; ++j) {
            float t = s[j];
            t += __shfl_xor(t, 1);
            t += __shfl_xor(t, 2);
            t += __shfl_xor(t, 4);
            t += __shfl_xor(t, 8);
            if (lr == 0)
                atomicAdd(&rowsum[row_base + mi * 16u + kg * 4u + j], t);
        }
    }
}

__global__ void lse_log(float* __restrict__ out) {
    int i = blockIdx.x * 256 + threadIdx.x;
    if (i < MD) out[i] = logf(out[i]);
}

extern "C" void kernel_launch(void* const* d_in, const int* in_sizes, int n_in,
                              void* d_out, int out_size, void* d_ws, size_t ws_size,
                              hipStream_t stream) {
    (void)in_sizes; (void)n_in; (void)out_size;
    const float* x = (const float*)d_in[0];
    const float* W = (const float*)d_in[1];
    const float* b = (const float*)d_in[2];
    float* out = (float*)d_out;

    hipMemsetAsync(out, 0, (size_t)MD * sizeof(float), stream);

    size_t need = ((size_t)MD * KD + (size_t)ND * KD) * sizeof(__bf16);  // 100.7 MB
    if (ws_size >= need) {
        __bf16* xb = (__bf16*)d_ws;
        __bf16* Wb = xb + (size_t)MD * KD;
        cvt_bf16<<<2048, 256, 0, stream>>>(x, xb, MD * KD / 8);
        cvt_bf16<<<2048, 256, 0, stream>>>(W, Wb, ND * KD / 8);
        gemm_bf16_lse<<<(MD / BMg) * (ND / BNg), 512, 0, stream>>>(xb, Wb, b, out);
    } else {
        fused_gemm_lse<<<NBLK, 512, 0, stream>>>(x, W, b, out);
    }
    lse_log<<<MD / 256, 256, 0, stream>>>(out);
}